// Round 7
// baseline (526.538 us; speedup 1.0000x reference)
//
#include <hip/hip_runtime.h>

// ---------------- problem constants ----------------
#define NVEC  131072      // 32*4096 vectors
#define DIM   64
#define K     512
#define DECAYF 0.99f
#define OMDF   0.01f
#define EPSF   1e-5f
#define NBLK_ASSIGN (NVEC / 64)   // 2048 blocks, 64 vectors each

// ---------------- output layout (floats, concatenated in return order) ----
#define Q_OFF    0
#define DIFF_OFF 8388608
#define IND_OFF  8388609
#define NE_OFF   8519681
#define NCS_OFF  8552449
#define NEA_OFF  8552961

// ---------------- ws layout (floats) — ~0.8 MB ----
#define ET_OFF    0        // E^T : K x DIM
#define C_OFF     32768    // np-order sum(E*E, axis=0) : K
#define CNT_OFF   33280    // counts : K             (written by vq_stats)
#define ESUM_OFF  33792    // segment sum : K x DIM  (written by vq_stats)
#define DPART_OFF 66560    // per-assign-block diff partials : 2048
#define INDI_OFF  68608    // int copy of indices : NVEC

// ============ prep: transpose embed -> E^T, C_j = np.sum(E*E, axis=0) ====
__global__ __launch_bounds__(256) void vq_prep(const float* __restrict__ embed,
                                               float* __restrict__ ws) {
    #pragma clang fp contract(off)
    int j = blockIdx.x * 256 + threadIdx.x;
    float c = 0.0f;
    for (int d = 0; d < DIM; ++d) {
        float v = embed[d * K + j];           // coalesced across j
        ws[ET_OFF + j * DIM + d] = v;
        float t = v * v;
        c = c + t;
    }
    ws[C_OFF + j] = c;
}

// ============ main: np-fp32-replica argmin, 4-way K-split ================
// Block = 4 waves x 64 vectors; wave w scans codes [w*128,(w+1)*128).
// waves_per_eu(4,4): allocator budget = 512/4 = 128 VGPRs, so f[64] is
// register-resident. (r4/r5: 64-VGPR max-occupancy target -> L1 reloads;
// r6: clobber alone -> 215 MB of scratch spills. Min AND max must be set.)
__global__ __launch_bounds__(256)
__attribute__((amdgpu_waves_per_eu(4, 4)))
void vq_assign(
    const float* __restrict__ x,
    const float* __restrict__ ET,      // ws + ET_OFF
    const float* __restrict__ C,       // ws + C_OFF
    int*   __restrict__ indI,          // ws + INDI_OFF
    float* __restrict__ dpart,         // ws + DPART_OFF
    float* __restrict__ out)
{
    #pragma clang fp contract(off)
    __shared__ float sd[4][64];
    __shared__ int   si[4][64];
    __shared__ int   sbest[64];
    __shared__ float wdl[4];

    int lane = threadIdx.x & 63;
    int wq   = __builtin_amdgcn_readfirstlane(threadIdx.x >> 6); // wave-uniform
    int v    = blockIdx.x * 64 + lane;
    const float* fx = x + (size_t)v * DIM;

    float f[DIM];
    #pragma unroll
    for (int k = 0; k < DIM / 4; ++k) {
        float4 t = ((const float4*)fx)[k];
        f[4*k+0] = t.x; f[4*k+1] = t.y; f[4*k+2] = t.z; f[4*k+3] = t.w;
    }
    // pin every f[d] in a VGPR; compiler cannot re-fold the global loads
    #pragma unroll
    for (int d = 0; d < DIM; ++d) asm volatile("" : "+v"(f[d]));

    // A = np.sum(f*f, axis=1): numpy pairwise, n=64 -> 8 accumulators over
    // strides of 8, then ((r0+r1)+(r2+r3))+((r4+r5)+(r6+r7)). Plain mul+add.
    float r[8];
    #pragma unroll
    for (int k = 0; k < 8; ++k) r[k] = f[k] * f[k];
    #pragma unroll
    for (int b = 1; b < 8; ++b) {
        #pragma unroll
        for (int k = 0; k < 8; ++k) {
            float t = f[8*b + k] * f[8*b + k];
            r[k] = r[k] + t;
        }
    }
    float A = ((r[0] + r[1]) + (r[2] + r[3])) + ((r[4] + r[5]) + (r[6] + r[7]));

    // scan this wave's 128 codes; j wave-uniform -> scalar loads for e,C.
    // Per-j fp32 sequence bit-identical to round-2 passing kernel.
    const float* eseg = ET + (size_t)wq * 128 * DIM;
    const float* Cseg = C + wq * 128;
    float bestd = 3.0e38f;
    int   besti = wq * 128;
    #pragma unroll 4
    for (int jj = 0; jj < 128; ++jj) {
        const float* e = eseg + jj * DIM;
        float m = 0.0f;
        #pragma unroll
        for (int d = 0; d < DIM; ++d) m = __builtin_fmaf(f[d], e[d], m);
        float t1 = 2.0f * m;             // exact (x2)
        float t2 = A - t1;               // rounded at ulp(~64)
        float dist = t2 + Cseg[jj];      // rounded
        if (dist < bestd) { bestd = dist; besti = wq * 128 + jj; }
    }

    sd[wq][lane] = bestd;
    si[wq][lane] = besti;
    __syncthreads();

    if (wq == 0) {
        float bd = sd[0][lane];
        int   bi = si[0][lane];
        #pragma unroll
        for (int q = 1; q < 4; ++q) {
            float d2 = sd[q][lane];
            int   i2 = si[q][lane];
            if (d2 < bd || (d2 == bd && i2 < bi)) { bd = d2; bi = i2; }
        }
        sbest[lane] = bi;
        out[IND_OFF + v] = (float)bi;    // coalesced
        indI[v] = bi;                    // int copy for vq_stats
    }
    __syncthreads();

    // epilogue: wave w handles a 16-float quarter of its own vector's row
    int bi = sbest[lane];
    const float* qrow = ET + (size_t)bi * DIM + wq * 16;
    float* orow = out + Q_OFF + (size_t)v * DIM + wq * 16;
    float dl = 0.0f;
    #pragma unroll
    for (int k = 0; k < 4; ++k) {
        float4 tq = ((const float4*)qrow)[k];
        float r0 = tq.x - f[wq*16 + 4*k+0];
        float r1 = tq.y - f[wq*16 + 4*k+1];
        float r2 = tq.z - f[wq*16 + 4*k+2];
        float r3 = tq.w - f[wq*16 + 4*k+3];
        dl = __builtin_fmaf(r0, r0, dl); dl = __builtin_fmaf(r1, r1, dl);
        dl = __builtin_fmaf(r2, r2, dl); dl = __builtin_fmaf(r3, r3, dl);
        ((float4*)orow)[k] = tq;
    }

    #pragma unroll
    for (int off = 32; off > 0; off >>= 1) dl += __shfl_down(dl, off);
    if (lane == 0) wdl[wq] = dl;
    __syncthreads();
    if (threadIdx.x == 0)
        dpart[blockIdx.x] = ((wdl[0] + wdl[1]) + (wdl[2] + wdl[3]));
}

// ============ stats: one block per code, ballot-compaction scan ==========
// Wave w scans ids [w*32768,(w+1)*32768): ballot finds matches (wave-
// uniform bit loop, no divergence); all 64 lanes gather each matching row
// coalesced (256 B). Counts via popcount. Zero atomics, zero extra passes.
__global__ __launch_bounds__(256) void vq_stats(
    const float* __restrict__ x,
    const int* __restrict__ indI,      // ws + INDI_OFF
    float* __restrict__ counts,        // ws + CNT_OFF
    float* __restrict__ esum)          // ws + ESUM_OFF
{
    __shared__ float p[4][DIM];
    __shared__ float c[4];
    int j    = blockIdx.x;
    int lane = threadIdx.x & 63;
    int w    = __builtin_amdgcn_readfirstlane(threadIdx.x >> 6);

    float acc = 0.0f;
    int   cnt = 0;
    int   base = w * (NVEC / 4);
    for (int i = 0; i < NVEC / 4; i += 64) {
        int idv = indI[base + i + lane];            // coalesced, L2-broadcast
        unsigned long long m = __ballot(idv == j);  // wave-uniform
        cnt += (int)__popcll(m);
        while (m) {
            int b = __builtin_ctzll(m);
            m &= m - 1;
            int vv = base + i + b;
            acc += x[(size_t)vv * DIM + lane];      // 256 B coalesced row
        }
    }
    p[w][lane] = acc;
    if (lane == 0) c[w] = (float)cnt;
    __syncthreads();
    if (w == 0) {
        esum[j * DIM + lane] = ((p[0][lane] + p[1][lane]) + (p[2][lane] + p[3][lane]));
        if (lane == 0) counts[j] = ((c[0] + c[1]) + (c[2] + c[3]));
    }
}

// ============ finalize: EMA updates + normalized codebook + diff ==========
__global__ __launch_bounds__(512) void vq_finalize(
    const float* __restrict__ cluster_size,
    const float* __restrict__ embed_avg,
    const float* __restrict__ ws,
    float* __restrict__ out)
{
    __shared__ float wsum[8];
    __shared__ float dsum_sh[8];
    __shared__ float n_sh;
    int j = threadIdx.x;  // 512 threads, one per code

    float ncs = DECAYF * cluster_size[j] + OMDF * ws[CNT_OFF + j];
    out[NCS_OFF + j] = ncs;

    // diff: sum 2048 block partials (deterministic)
    float dsum = 0.0f;
    #pragma unroll
    for (int k = 0; k < NBLK_ASSIGN / 512; ++k)
        dsum += ws[DPART_OFF + k * 512 + j];

    float s = ncs;
    #pragma unroll
    for (int off = 32; off > 0; off >>= 1) {
        s    += __shfl_down(s, off);
        dsum += __shfl_down(dsum, off);
    }
    if ((j & 63) == 0) { wsum[j >> 6] = s; dsum_sh[j >> 6] = dsum; }
    __syncthreads();
    if (j == 0) {
        float n = 0.f, dtot = 0.f;
        #pragma unroll
        for (int w = 0; w < 8; ++w) { n += wsum[w]; dtot += dsum_sh[w]; }
        n_sh = n;
        out[DIFF_OFF] = dtot * (1.0f / 8388608.0f);  // 2^23: exact
    }
    __syncthreads();
    float n   = n_sh;
    float csz = (ncs + EPSF) / (n + (float)K * EPSF) * n;

    #pragma unroll 4
    for (int d = 0; d < DIM; ++d) {
        float ea = DECAYF * embed_avg[d * K + j] + OMDF * ws[ESUM_OFF + j * DIM + d];
        out[NEA_OFF + d * K + j] = ea;        // coalesced over j
        out[NE_OFF  + d * K + j] = ea / csz;
    }
}

// ============ launch ============
extern "C" void kernel_launch(void* const* d_in, const int* in_sizes, int n_in,
                              void* d_out, int out_size, void* d_ws, size_t ws_size,
                              hipStream_t stream) {
    const float* x            = (const float*)d_in[0];
    const float* embed        = (const float*)d_in[1];
    const float* cluster_size = (const float*)d_in[2];
    const float* embed_avg    = (const float*)d_in[3];
    float* out = (float*)d_out;
    float* ws  = (float*)d_ws;
    int*   indI = (int*)(ws + INDI_OFF);

    vq_prep<<<K / 256, 256, 0, stream>>>(embed, ws);
    vq_assign<<<NBLK_ASSIGN, 256, 0, stream>>>(
        x, ws + ET_OFF, ws + C_OFF, indI, ws + DPART_OFF, out);
    vq_stats<<<K, 256, 0, stream>>>(x, indI, ws + CNT_OFF, ws + ESUM_OFF);
    vq_finalize<<<1, K, 0, stream>>>(cluster_size, embed_avg, ws, out);
}

// Round 8
// 364.215 us; speedup vs baseline: 1.4457x; 1.4457x over previous
//
#include <hip/hip_runtime.h>

// ---------------- problem constants ----------------
#define NVEC  131072      // 32*4096 vectors
#define DIM   64
#define K     512
#define DECAYF 0.99f
#define OMDF   0.01f
#define EPSF   1e-5f
#define NBLK_ASSIGN (NVEC / 64)   // 2048 blocks, 64 vectors each

// ---------------- output layout (floats, concatenated in return order) ----
#define Q_OFF    0
#define DIFF_OFF 8388608
#define IND_OFF  8388609
#define NE_OFF   8519681
#define NCS_OFF  8552449
#define NEA_OFF  8552961

// ---------------- ws layout (floats) — ~1.2 MB ----
#define ET_OFF    0        // E^T : K x DIM
#define C_OFF     32768    // np-order sum(E*E, axis=0) : K
#define DPART_OFF 33280    // per-assign-block diff partials : 2048
#define INDI_OFF  35328    // int copy of indices : NVEC
#define PCNT_OFF  166400   // count partials : 4 x K
#define PESUM_OFF 168448   // esum partials : 4 x K x DIM
// end: 299520 floats = 1.17 MB

// ============ prep: transpose embed -> E^T, C_j = np.sum(E*E, axis=0) ====
__global__ __launch_bounds__(256) void vq_prep(const float* __restrict__ embed,
                                               float* __restrict__ ws) {
    #pragma clang fp contract(off)
    int j = blockIdx.x * 256 + threadIdx.x;
    float c = 0.0f;
    for (int d = 0; d < DIM; ++d) {
        float v = embed[d * K + j];           // coalesced across j
        ws[ET_OFF + j * DIM + d] = v;
        float t = v * v;
        c = c + t;
    }
    ws[C_OFF + j] = c;
}

// ============ main: np-fp32-replica argmin, 4-way K-split ================
// Block = 4 waves x 64 vectors; wave w scans codes [w*128,(w+1)*128).
// f[64] register-residency needs ALL THREE: (a) static indexing only
// (r6/r7's f[wq*16+k] dynamic index forced the array to scratch: 215 MB
// WRITE_SIZE), (b) asm clobber so loads can't be rematerialized from L1
// (r4/r5: 40 VGPRs + reloads), (c) waves_per_eu(4,4) for a 128-VGPR budget.
__global__ __launch_bounds__(256)
__attribute__((amdgpu_waves_per_eu(4, 4)))
void vq_assign(
    const float* __restrict__ x,
    const float* __restrict__ ET,      // ws + ET_OFF
    const float* __restrict__ C,       // ws + C_OFF
    int*   __restrict__ indI,          // ws + INDI_OFF
    float* __restrict__ dpart,         // ws + DPART_OFF
    float* __restrict__ out)
{
    #pragma clang fp contract(off)
    __shared__ float sd[4][64];
    __shared__ int   si[4][64];
    __shared__ int   sbest[64];
    __shared__ float wdl[4];

    int lane = threadIdx.x & 63;
    int wq   = __builtin_amdgcn_readfirstlane(threadIdx.x >> 6); // wave-uniform
    int v    = blockIdx.x * 64 + lane;
    const float* fx = x + (size_t)v * DIM;

    float f[DIM];
    #pragma unroll
    for (int k = 0; k < DIM / 4; ++k) {
        float4 t = ((const float4*)fx)[k];
        f[4*k+0] = t.x; f[4*k+1] = t.y; f[4*k+2] = t.z; f[4*k+3] = t.w;
    }
    // pin every f[d] in a VGPR; compiler cannot re-fold the global loads
    #pragma unroll
    for (int d = 0; d < DIM; ++d) asm volatile("" : "+v"(f[d]));

    // A = np.sum(f*f, axis=1): numpy pairwise, n=64 -> 8 accumulators over
    // strides of 8, then ((r0+r1)+(r2+r3))+((r4+r5)+(r6+r7)). Plain mul+add.
    float r[8];
    #pragma unroll
    for (int k = 0; k < 8; ++k) r[k] = f[k] * f[k];
    #pragma unroll
    for (int b = 1; b < 8; ++b) {
        #pragma unroll
        for (int k = 0; k < 8; ++k) {
            float t = f[8*b + k] * f[8*b + k];
            r[k] = r[k] + t;
        }
    }
    float A = ((r[0] + r[1]) + (r[2] + r[3])) + ((r[4] + r[5]) + (r[6] + r[7]));

    // scan this wave's 128 codes; j wave-uniform -> scalar loads for e,C.
    // Per-j fp32 sequence bit-identical to round-2 passing kernel.
    const float* eseg = ET + (size_t)wq * 128 * DIM;
    const float* Cseg = C + wq * 128;
    float bestd = 3.0e38f;
    int   besti = wq * 128;
    #pragma unroll 4
    for (int jj = 0; jj < 128; ++jj) {
        const float* e = eseg + jj * DIM;
        float m = 0.0f;
        #pragma unroll
        for (int d = 0; d < DIM; ++d) m = __builtin_fmaf(f[d], e[d], m);
        float t1 = 2.0f * m;             // exact (x2)
        float t2 = A - t1;               // rounded at ulp(~64)
        float dist = t2 + Cseg[jj];      // rounded
        if (dist < bestd) { bestd = dist; besti = wq * 128 + jj; }
    }

    sd[wq][lane] = bestd;
    si[wq][lane] = besti;
    __syncthreads();

    if (wq == 0) {
        float bd = sd[0][lane];
        int   bi = si[0][lane];
        #pragma unroll
        for (int q = 1; q < 4; ++q) {
            float d2 = sd[q][lane];
            int   i2 = si[q][lane];
            if (d2 < bd || (d2 == bd && i2 < bi)) { bd = d2; bi = i2; }
        }
        sbest[lane] = bi;
        out[IND_OFF + v] = (float)bi;    // coalesced
        indI[v] = bi;                    // int copy for vq_stats
    }
    __syncthreads();

    // epilogue: wave w handles a 16-float quarter of each row.
    // STATIC indexing only — x quarter reloaded from global (L1-hot).
    int bi = sbest[lane];
    const float* qrow = ET + (size_t)bi * DIM + wq * 16;
    const float* xrow = fx + wq * 16;
    float* orow = out + Q_OFF + (size_t)v * DIM + wq * 16;
    float dl = 0.0f;
    #pragma unroll
    for (int k = 0; k < 4; ++k) {
        float4 tq = ((const float4*)qrow)[k];
        float4 tx = ((const float4*)xrow)[k];
        float r0 = tq.x - tx.x;
        float r1 = tq.y - tx.y;
        float r2 = tq.z - tx.z;
        float r3 = tq.w - tx.w;
        dl = __builtin_fmaf(r0, r0, dl); dl = __builtin_fmaf(r1, r1, dl);
        dl = __builtin_fmaf(r2, r2, dl); dl = __builtin_fmaf(r3, r3, dl);
        ((float4*)orow)[k] = tq;
    }

    #pragma unroll
    for (int off = 32; off > 0; off >>= 1) dl += __shfl_down(dl, off);
    if (lane == 0) wdl[wq] = dl;
    __syncthreads();
    if (threadIdx.x == 0)
        dpart[blockIdx.x] = ((wdl[0] + wdl[1]) + (wdl[2] + wdl[3]));
}

// ============ stats: 4 blocks per code, int4 ballot-compaction scan ======
// Block (j = bid>>2, q = bid&3); wave w scans segment q*4+w (8192 ids) as
// int4 (4 independent ballots per load, 32 iterations). Matching rows are
// gathered by all 64 lanes coalesced. Partials out; finalize reduces 4.
__global__ __launch_bounds__(256) void vq_stats(
    const float* __restrict__ x,
    const int* __restrict__ indI,      // ws + INDI_OFF
    float* __restrict__ pcnt,          // ws + PCNT_OFF   [4][K]
    float* __restrict__ pesum)         // ws + PESUM_OFF  [4][K][DIM]
{
    __shared__ float p[4][DIM];
    __shared__ float c[4];
    int j    = blockIdx.x >> 2;
    int q    = blockIdx.x & 3;
    int lane = threadIdx.x & 63;
    int w    = __builtin_amdgcn_readfirstlane(threadIdx.x >> 6);

    int seg  = q * 4 + w;              // 0..15
    int base = seg * (NVEC / 16);      // 8192 ids per segment

    float acc = 0.0f;
    int   cnt = 0;
    for (int i = 0; i < NVEC / 16; i += 256) {
        int4 idv = ((const int4*)(indI + base + i))[lane];  // 256 ids/wave
        unsigned long long m0 = __ballot(idv.x == j);
        unsigned long long m1 = __ballot(idv.y == j);
        unsigned long long m2 = __ballot(idv.z == j);
        unsigned long long m3 = __ballot(idv.w == j);
        cnt += (int)(__popcll(m0) + __popcll(m1) + __popcll(m2) + __popcll(m3));
        while (m0) { int b = __builtin_ctzll(m0); m0 &= m0 - 1;
                     acc += x[(size_t)(base + i + 4*b + 0) * DIM + lane]; }
        while (m1) { int b = __builtin_ctzll(m1); m1 &= m1 - 1;
                     acc += x[(size_t)(base + i + 4*b + 1) * DIM + lane]; }
        while (m2) { int b = __builtin_ctzll(m2); m2 &= m2 - 1;
                     acc += x[(size_t)(base + i + 4*b + 2) * DIM + lane]; }
        while (m3) { int b = __builtin_ctzll(m3); m3 &= m3 - 1;
                     acc += x[(size_t)(base + i + 4*b + 3) * DIM + lane]; }
    }
    p[w][lane] = acc;
    if (lane == 0) c[w] = (float)cnt;
    __syncthreads();
    if (w == 0) {
        pesum[((size_t)q * K + j) * DIM + lane] =
            ((p[0][lane] + p[1][lane]) + (p[2][lane] + p[3][lane]));
        if (lane == 0) pcnt[q * K + j] = ((c[0] + c[1]) + (c[2] + c[3]));
    }
}

// ============ finalize: reduce partials + EMA + normalize + diff ==========
__global__ __launch_bounds__(512) void vq_finalize(
    const float* __restrict__ cluster_size,
    const float* __restrict__ embed_avg,
    const float* __restrict__ ws,
    float* __restrict__ out)
{
    __shared__ float wsum[8];
    __shared__ float dsum_sh[8];
    __shared__ float n_sh;
    int j = threadIdx.x;  // 512 threads, one per code

    float cj = ((ws[PCNT_OFF + 0*K + j] + ws[PCNT_OFF + 1*K + j])
              + (ws[PCNT_OFF + 2*K + j] + ws[PCNT_OFF + 3*K + j]));
    float ncs = DECAYF * cluster_size[j] + OMDF * cj;
    out[NCS_OFF + j] = ncs;

    // diff: sum 2048 block partials (deterministic)
    float dsum = 0.0f;
    #pragma unroll
    for (int k = 0; k < NBLK_ASSIGN / 512; ++k)
        dsum += ws[DPART_OFF + k * 512 + j];

    float s = ncs;
    #pragma unroll
    for (int off = 32; off > 0; off >>= 1) {
        s    += __shfl_down(s, off);
        dsum += __shfl_down(dsum, off);
    }
    if ((j & 63) == 0) { wsum[j >> 6] = s; dsum_sh[j >> 6] = dsum; }
    __syncthreads();
    if (j == 0) {
        float n = 0.f, dtot = 0.f;
        #pragma unroll
        for (int w = 0; w < 8; ++w) { n += wsum[w]; dtot += dsum_sh[w]; }
        n_sh = n;
        out[DIFF_OFF] = dtot * (1.0f / 8388608.0f);  // 2^23: exact
    }
    __syncthreads();
    float n   = n_sh;
    float csz = (ncs + EPSF) / (n + (float)K * EPSF) * n;

    #pragma unroll 4
    for (int d = 0; d < DIM; ++d) {
        float es = ((ws[PESUM_OFF + ((size_t)0*K + j) * DIM + d]
                   + ws[PESUM_OFF + ((size_t)1*K + j) * DIM + d])
                  + (ws[PESUM_OFF + ((size_t)2*K + j) * DIM + d]
                   + ws[PESUM_OFF + ((size_t)3*K + j) * DIM + d]));
        float ea = DECAYF * embed_avg[d * K + j] + OMDF * es;
        out[NEA_OFF + d * K + j] = ea;        // coalesced over j
        out[NE_OFF  + d * K + j] = ea / csz;
    }
}

// ============ launch ============
extern "C" void kernel_launch(void* const* d_in, const int* in_sizes, int n_in,
                              void* d_out, int out_size, void* d_ws, size_t ws_size,
                              hipStream_t stream) {
    const float* x            = (const float*)d_in[0];
    const float* embed        = (const float*)d_in[1];
    const float* cluster_size = (const float*)d_in[2];
    const float* embed_avg    = (const float*)d_in[3];
    float* out = (float*)d_out;
    float* ws  = (float*)d_ws;
    int*   indI = (int*)(ws + INDI_OFF);

    vq_prep<<<K / 256, 256, 0, stream>>>(embed, ws);
    vq_assign<<<NBLK_ASSIGN, 256, 0, stream>>>(
        x, ws + ET_OFF, ws + C_OFF, indI, ws + DPART_OFF, out);
    vq_stats<<<K * 4, 256, 0, stream>>>(
        x, indI, ws + PCNT_OFF, ws + PESUM_OFF);
    vq_finalize<<<1, K, 0, stream>>>(cluster_size, embed_avg, ws, out);
}

// Round 9
// 297.836 us; speedup vs baseline: 1.7679x; 1.2229x over previous
//
#include <hip/hip_runtime.h>

// ---------------- problem constants ----------------
#define NVEC  131072      // 32*4096 vectors
#define DIM   64
#define K     512
#define DECAYF 0.99f
#define OMDF   0.01f
#define EPSF   1e-5f
#define NBLK_ASSIGN (NVEC / 64)   // 2048 blocks, 64 vectors each

// ---------------- output layout (floats, concatenated in return order) ----
#define Q_OFF    0
#define DIFF_OFF 8388608
#define IND_OFF  8388609
#define NE_OFF   8519681
#define NCS_OFF  8552449
#define NEA_OFF  8552961

// ---------------- ws layout (floats) — ~1.2 MB ----
#define ET_OFF    0        // E^T : K x DIM
#define C_OFF     32768    // np-order sum(E*E, axis=0) : K
#define DPART_OFF 33280    // per-assign-block diff partials : 2048
#define INDI_OFF  35328    // int copy of indices : NVEC
#define PCNT_OFF  166400   // count partials : 4 x K
#define PESUM_OFF 168448   // esum partials : 4 x K x DIM
// end: 299520 floats = 1.17 MB (known-safe: r4 used 1.33 MB)

// ============ prep: transpose embed -> E^T, C_j = np.sum(E*E, axis=0) ====
__global__ __launch_bounds__(256) void vq_prep(const float* __restrict__ embed,
                                               float* __restrict__ ws) {
    #pragma clang fp contract(off)
    int j = blockIdx.x * 256 + threadIdx.x;
    float c = 0.0f;
    for (int d = 0; d < DIM; ++d) {
        float v = embed[d * K + j];           // coalesced across j
        ws[ET_OFF + j * DIM + d] = v;
        float t = v * v;
        c = c + t;
    }
    ws[C_OFF + j] = c;
}

// ============ main: np-fp32-replica argmin, 4-way K-split ================
// Body is r4-exact (all-static indexing, no clobber — the only form proven
// spill-free). Single new lever: waves_per_eu(4,8) raises the allocator's
// VGPR budget to 128 so keeping f[64] resident is cheaper than the r4
// behavior of rematerializing x loads from L1 inside the j-loop.
__global__ __launch_bounds__(256)
__attribute__((amdgpu_waves_per_eu(4, 8)))
void vq_assign(
    const float* __restrict__ x,
    const float* __restrict__ ET,      // ws + ET_OFF
    const float* __restrict__ C,       // ws + C_OFF
    int*   __restrict__ indI,          // ws + INDI_OFF
    float* __restrict__ dpart,         // ws + DPART_OFF
    float* __restrict__ out)
{
    #pragma clang fp contract(off)
    __shared__ float sd[4][64];
    __shared__ int   si[4][64];
    __shared__ int   sbest[64];
    __shared__ float wdl[4];

    int lane = threadIdx.x & 63;
    int wq   = __builtin_amdgcn_readfirstlane(threadIdx.x >> 6); // wave-uniform
    int v    = blockIdx.x * 64 + lane;
    const float* fx = x + (size_t)v * DIM;

    float f[DIM];
    #pragma unroll
    for (int k = 0; k < DIM / 4; ++k) {
        float4 t = ((const float4*)fx)[k];
        f[4*k+0] = t.x; f[4*k+1] = t.y; f[4*k+2] = t.z; f[4*k+3] = t.w;
    }

    // A = np.sum(f*f, axis=1): numpy pairwise, n=64 -> 8 accumulators over
    // strides of 8, then ((r0+r1)+(r2+r3))+((r4+r5)+(r6+r7)). Plain mul+add.
    float r[8];
    #pragma unroll
    for (int k = 0; k < 8; ++k) r[k] = f[k] * f[k];
    #pragma unroll
    for (int b = 1; b < 8; ++b) {
        #pragma unroll
        for (int k = 0; k < 8; ++k) {
            float t = f[8*b + k] * f[8*b + k];
            r[k] = r[k] + t;
        }
    }
    float A = ((r[0] + r[1]) + (r[2] + r[3])) + ((r[4] + r[5]) + (r[6] + r[7]));

    // scan this wave's 128 codes; j wave-uniform -> scalar loads for e,C.
    // Per-j fp32 sequence bit-identical to round-2 passing kernel.
    const float* eseg = ET + (size_t)wq * 128 * DIM;
    const float* Cseg = C + wq * 128;
    float bestd = 3.0e38f;
    int   besti = wq * 128;
    #pragma unroll 4
    for (int jj = 0; jj < 128; ++jj) {
        const float* e = eseg + jj * DIM;
        float m = 0.0f;
        #pragma unroll
        for (int d = 0; d < DIM; ++d) m = __builtin_fmaf(f[d], e[d], m);
        float t1 = 2.0f * m;             // exact (x2)
        float t2 = A - t1;               // rounded at ulp(~64)
        float dist = t2 + Cseg[jj];      // rounded
        if (dist < bestd) { bestd = dist; besti = wq * 128 + jj; }
    }

    sd[wq][lane] = bestd;
    si[wq][lane] = besti;
    __syncthreads();

    if (wq == 0) {
        float bd = sd[0][lane];
        int   bi = si[0][lane];
        #pragma unroll
        for (int q = 1; q < 4; ++q) {
            float d2 = sd[q][lane];
            int   i2 = si[q][lane];
            if (d2 < bd || (d2 == bd && i2 < bi)) { bd = d2; bi = i2; }
        }
        sbest[lane] = bi;
        out[IND_OFF + v] = (float)bi;    // coalesced
        indI[v] = bi;                    // int copy for vq_stats
    }
    __syncthreads();

    // epilogue: wave w handles a 16-float quarter of each row.
    // STATIC indexing only — x quarter reloaded from global (L1-hot).
    int bi = sbest[lane];
    const float* qrow = ET + (size_t)bi * DIM + wq * 16;
    const float* xrow = fx + wq * 16;
    float* orow = out + Q_OFF + (size_t)v * DIM + wq * 16;
    float dl = 0.0f;
    #pragma unroll
    for (int k = 0; k < 4; ++k) {
        float4 tq = ((const float4*)qrow)[k];
        float4 tx = ((const float4*)xrow)[k];
        float r0 = tq.x - tx.x;
        float r1 = tq.y - tx.y;
        float r2 = tq.z - tx.z;
        float r3 = tq.w - tx.w;
        dl = __builtin_fmaf(r0, r0, dl); dl = __builtin_fmaf(r1, r1, dl);
        dl = __builtin_fmaf(r2, r2, dl); dl = __builtin_fmaf(r3, r3, dl);
        ((float4*)orow)[k] = tq;
    }

    #pragma unroll
    for (int off = 32; off > 0; off >>= 1) dl += __shfl_down(dl, off);
    if (lane == 0) wdl[wq] = dl;
    __syncthreads();
    if (threadIdx.x == 0)
        dpart[blockIdx.x] = ((wdl[0] + wdl[1]) + (wdl[2] + wdl[3]));
}

// ============ stats: 4 blocks x 8 waves per code, int4 ballot scan =======
// Block (j = bid>>2, q = bid&3); wave w scans segment q*8+w (4096 ids) as
// int4 (4 independent ballots per load, 16 iterations). Matching rows are
// gathered by all 64 lanes coalesced. Partials out; finalize reduces 4.
__global__ __launch_bounds__(512) void vq_stats(
    const float* __restrict__ x,
    const int* __restrict__ indI,      // ws + INDI_OFF
    float* __restrict__ pcnt,          // ws + PCNT_OFF   [4][K]
    float* __restrict__ pesum)         // ws + PESUM_OFF  [4][K][DIM]
{
    __shared__ float p[8][DIM];
    __shared__ float c[8];
    int j    = blockIdx.x >> 2;
    int q    = blockIdx.x & 3;
    int lane = threadIdx.x & 63;
    int w    = __builtin_amdgcn_readfirstlane(threadIdx.x >> 6);

    int seg  = q * 8 + w;              // 0..31
    int base = seg * (NVEC / 32);      // 4096 ids per segment

    float acc = 0.0f;
    int   cnt = 0;
    for (int i = 0; i < NVEC / 32; i += 256) {
        int4 idv = ((const int4*)(indI + base + i))[lane];  // 256 ids/wave
        unsigned long long m0 = __ballot(idv.x == j);
        unsigned long long m1 = __ballot(idv.y == j);
        unsigned long long m2 = __ballot(idv.z == j);
        unsigned long long m3 = __ballot(idv.w == j);
        cnt += (int)(__popcll(m0) + __popcll(m1) + __popcll(m2) + __popcll(m3));
        while (m0) { int b = __builtin_ctzll(m0); m0 &= m0 - 1;
                     acc += x[(size_t)(base + i + 4*b + 0) * DIM + lane]; }
        while (m1) { int b = __builtin_ctzll(m1); m1 &= m1 - 1;
                     acc += x[(size_t)(base + i + 4*b + 1) * DIM + lane]; }
        while (m2) { int b = __builtin_ctzll(m2); m2 &= m2 - 1;
                     acc += x[(size_t)(base + i + 4*b + 2) * DIM + lane]; }
        while (m3) { int b = __builtin_ctzll(m3); m3 &= m3 - 1;
                     acc += x[(size_t)(base + i + 4*b + 3) * DIM + lane]; }
    }
    p[w][lane] = acc;
    if (lane == 0) c[w] = (float)cnt;
    __syncthreads();
    if (w == 0) {
        float s = ((p[0][lane] + p[1][lane]) + (p[2][lane] + p[3][lane]))
                + ((p[4][lane] + p[5][lane]) + (p[6][lane] + p[7][lane]));
        pesum[((size_t)q * K + j) * DIM + lane] = s;
        if (lane == 0)
            pcnt[q * K + j] = ((c[0] + c[1]) + (c[2] + c[3]))
                            + ((c[4] + c[5]) + (c[6] + c[7]));
    }
}

// ============ finalize: reduce partials + EMA + normalize + diff ==========
__global__ __launch_bounds__(512) void vq_finalize(
    const float* __restrict__ cluster_size,
    const float* __restrict__ embed_avg,
    const float* __restrict__ ws,
    float* __restrict__ out)
{
    __shared__ float wsum[8];
    __shared__ float dsum_sh[8];
    __shared__ float n_sh;
    int j = threadIdx.x;  // 512 threads, one per code

    float cj = ((ws[PCNT_OFF + 0*K + j] + ws[PCNT_OFF + 1*K + j])
              + (ws[PCNT_OFF + 2*K + j] + ws[PCNT_OFF + 3*K + j]));
    float ncs = DECAYF * cluster_size[j] + OMDF * cj;
    out[NCS_OFF + j] = ncs;

    // diff: sum 2048 block partials (deterministic)
    float dsum = 0.0f;
    #pragma unroll
    for (int k = 0; k < NBLK_ASSIGN / 512; ++k)
        dsum += ws[DPART_OFF + k * 512 + j];

    float s = ncs;
    #pragma unroll
    for (int off = 32; off > 0; off >>= 1) {
        s    += __shfl_down(s, off);
        dsum += __shfl_down(dsum, off);
    }
    if ((j & 63) == 0) { wsum[j >> 6] = s; dsum_sh[j >> 6] = dsum; }
    __syncthreads();
    if (j == 0) {
        float n = 0.f, dtot = 0.f;
        #pragma unroll
        for (int w = 0; w < 8; ++w) { n += wsum[w]; dtot += dsum_sh[w]; }
        n_sh = n;
        out[DIFF_OFF] = dtot * (1.0f / 8388608.0f);  // 2^23: exact
    }
    __syncthreads();
    float n   = n_sh;
    float csz = (ncs + EPSF) / (n + (float)K * EPSF) * n;

    #pragma unroll 4
    for (int d = 0; d < DIM; ++d) {
        float es = ((ws[PESUM_OFF + ((size_t)0*K + j) * DIM + d]
                   + ws[PESUM_OFF + ((size_t)1*K + j) * DIM + d])
                  + (ws[PESUM_OFF + ((size_t)2*K + j) * DIM + d]
                   + ws[PESUM_OFF + ((size_t)3*K + j) * DIM + d]));
        float ea = DECAYF * embed_avg[d * K + j] + OMDF * es;
        out[NEA_OFF + d * K + j] = ea;        // coalesced over j
        out[NE_OFF  + d * K + j] = ea / csz;
    }
}

// ============ launch ============
extern "C" void kernel_launch(void* const* d_in, const int* in_sizes, int n_in,
                              void* d_out, int out_size, void* d_ws, size_t ws_size,
                              hipStream_t stream) {
    const float* x            = (const float*)d_in[0];
    const float* embed        = (const float*)d_in[1];
    const float* cluster_size = (const float*)d_in[2];
    const float* embed_avg    = (const float*)d_in[3];
    float* out = (float*)d_out;
    float* ws  = (float*)d_ws;
    int*   indI = (int*)(ws + INDI_OFF);

    vq_prep<<<K / 256, 256, 0, stream>>>(embed, ws);
    vq_assign<<<NBLK_ASSIGN, 256, 0, stream>>>(
        x, ws + ET_OFF, ws + C_OFF, indI, ws + DPART_OFF, out);
    vq_stats<<<K * 4, 512, 0, stream>>>(
        x, indI, ws + PCNT_OFF, ws + PESUM_OFF);
    vq_finalize<<<1, K, 0, stream>>>(cluster_size, embed_avg, ws, out);
}